// Round 5
// baseline (1129.092 us; speedup 1.0000x reference)
//
#include <hip/hip_runtime.h>
#include <stdint.h>

// SpikingLinearLayer: spikes = LIF_scan(x @ W^T)  -- exact i8-limb MFMA path.
//   x: [20, 1024, 2048] fp32 binary; W: [2048, 2048] fp32; out fp32 binary.
//
// R4 -> R5 (attack the barrier-drain plateau: MfmaUtil was stuck at 29%):
//  * A (x) fragments loaded DIRECT global->VGPR (16 rows x 64B per wave-load,
//    fully coalesced; block's 4 waves read identical addresses -> L1 hits).
//    No A staging, no A LDS traffic, barrier only covers B.
//  * KC=128: B-only LDS buffer 32 KB x2 = 64 KB/block -> still 2 blocks/CU.
//    Halves iteration count (160 barriers), 2x MFMA per barrier:
//    MFMA-busy/SIMD/iter = 2612 cyc vs ~1000 cyc fixed stall.
//  * Q=4 limbs (scale 2^30) exact-integer GEMM, fp64 recombine + LIF (R3/R4
//    verified absmax 0.0). i32 digit sums bounded by 2048*128 = 2^18.

constexpr int T_STEPS = 20;
constexpr int BATCH   = 1024;
constexpr int NIN     = 2048;
constexpr int NOUT    = 2048;

constexpr int    Q         = 4;
constexpr double SCALE     = 1073741824.0;     // 2^30
constexpr double INV_SCALE = 1.0 / SCALE;

constexpr size_t XI8_BYTES   = (size_t)T_STEPS * BATCH * NIN;        // 40 MB
constexpr size_t PLANE_BYTES = (size_t)NOUT * NIN;                   // 4 MB
constexpr size_t WS_NEEDED   = XI8_BYTES + (size_t)Q * PLANE_BYTES;  // 56 MB

typedef int v4i __attribute__((ext_vector_type(4)));

// async 16B/lane global->LDS DMA: lds dst = uniform base + lane*16
__device__ __forceinline__ void dma16(const int8_t* g, const int8_t* l) {
    __builtin_amdgcn_global_load_lds(
        (const __attribute__((address_space(1))) void*)(uintptr_t)g,
        (__attribute__((address_space(3))) void*)(uint32_t)(uintptr_t)l,
        16, 0, 0);
}

// ---------------------------------------------------------------- prep: x -> i8
__global__ void prep_x(const float* __restrict__ x, int8_t* __restrict__ xi) {
    const int idx = blockIdx.x * blockDim.x + threadIdx.x;   // 16 elems each
    const float4* xg = reinterpret_cast<const float4*>(x) + idx * 4;
    int8_t c[16];
#pragma unroll
    for (int q = 0; q < 4; ++q) {
        const float4 v = xg[q];
        c[q * 4 + 0] = (int8_t)(v.x != 0.0f);
        c[q * 4 + 1] = (int8_t)(v.y != 0.0f);
        c[q * 4 + 2] = (int8_t)(v.z != 0.0f);
        c[q * 4 + 3] = (int8_t)(v.w != 0.0f);
    }
    reinterpret_cast<v4i*>(xi)[idx] = *reinterpret_cast<const v4i*>(c);
}

// ------------------------------------------------- prep: W -> 4 base-256 digits
__global__ void prep_limbs(const float* __restrict__ w, int8_t* __restrict__ limbs) {
    const int idx = blockIdx.x * blockDim.x + threadIdx.x;   // 4 weights each
    const float4 wv = reinterpret_cast<const float4*>(w)[idx];
    const float wf[4] = {wv.x, wv.y, wv.z, wv.w};
    int8_t d[Q][4];
#pragma unroll
    for (int e = 0; e < 4; ++e) {
        long long M = llrint((double)wf[e] * SCALE);         // |M| < 2^30
#pragma unroll
        for (int j = 0; j < Q - 1; ++j) {
            const int dj = (int)((M + 128) & 255) - 128;
            d[j][e] = (int8_t)dj;
            M = (M - dj) >> 8;                               // exact
        }
        d[Q - 1][e] = (int8_t)M;                             // |top| <= 65
    }
#pragma unroll
    for (int j = 0; j < Q; ++j)
        reinterpret_cast<char4*>(limbs + (size_t)j * PLANE_BYTES)[idx] =
            make_char4(d[j][0], d[j][1], d[j][2], d[j][3]);
}

// --------------------------------------------------------------- hot: i8 GEMMs
constexpr int KC     = 128;
constexpr int NKC    = NIN / KC;            // 16
constexpr int NTB    = T_STEPS / 2;         // 10 t-pairs
constexpr int NITER  = NTB * NKC;           // 160
constexpr int BUF_B  = 32768;               // B only: 4 planes x 128k x 64o

__global__ __launch_bounds__(256, 2)
void snn_i8(const int8_t* __restrict__ xi, const int8_t* __restrict__ limbs,
            float* __restrict__ out)
{
    // XCD swizzle: 4 o-tiles pinned per XCD -> limb set 2 MB in 4 MB L2
    const int bid   = blockIdx.x;
    const int xcd   = bid & 7;
    const int sub   = bid >> 3;
    const int otile = xcd * 4 + (sub & 3);
    const int btile = sub >> 2;
    const int o0 = otile * 64, b0 = btile * 64;

    const int tid  = threadIdx.x;
    const int w    = tid >> 6;     // wave id = o j-group
    const int ln   = tid & 63;
    const int lm   = ln & 15;
    const int qd   = ln >> 4;

    __shared__ __align__(16) int8_t lds[2][BUF_B];

    // per-lane byte offsets
    const int l_lane = (o0 + 16 * w + lm) * NIN + qd * 16;   // limb source
    const int x_lane = (b0 + lm) * NIN + qd * 16;            // x row base (mg=0)

    // LIF state: lane elems e = mg*4+r -> b = b0+16mg+4qd+r, o = o0+16w+lm
    double V[16], I[16];
#pragma unroll
    for (int e = 0; e < 16; ++e) { V[e] = 0.0; I[e] = 0.0; }

    const double alpha_m = 1.0 - 1.0 / 20.0;
    const double alpha_s = 1.0 - 1.0 / 5.0;
    const double dtm     = 1.0 / 20.0;

    // B layout in buffer: j*8192 + kq*4096 + w*1024 + ln*16 (lane-contiguous,
    // identical pattern for DMA deposit and ds_read_b128 -> conflict-free)
    auto stageB = [&](int s) {
        const int kc = (s & (NKC - 1)) << 7;
        int8_t* lb = &lds[s & 1][0];
#pragma unroll
        for (int j = 0; j < Q; ++j)
#pragma unroll
            for (int kq = 0; kq < 2; ++kq)
                dma16(limbs + (size_t)j * PLANE_BYTES + kc + kq * 64 + l_lane,
                      lb + j * 8192 + kq * 4096 + w * 1024);
    };

    stageB(0);
    __syncthreads();

    int s = 0;
    for (int tb = 0; tb < NTB; ++tb) {
        const int8_t* xt0 = xi + (size_t)(2 * tb) * BATCH * NIN + x_lane;
        const int8_t* xt1 = xt0 + (size_t)BATCH * NIN;

        v4i acc0[4][4], acc1[4][4];   // [mg][plane]
#pragma unroll
        for (int mg = 0; mg < 4; ++mg)
#pragma unroll
            for (int j = 0; j < Q; ++j) {
                acc0[mg][j] = (v4i){0, 0, 0, 0};
                acc1[mg][j] = (v4i){0, 0, 0, 0};
            }

        for (int kci = 0; kci < NKC; ++kci, ++s) {
            if (s + 1 < NITER) stageB(s + 1);           // async prefetch (B only)

            const int kc = kci << 7;
            const int8_t* cb = &lds[s & 1][0];
#pragma unroll
            for (int kq = 0; kq < 2; ++kq) {
                v4i B[4];
#pragma unroll
                for (int j = 0; j < Q; ++j)
                    B[j] = *reinterpret_cast<const v4i*>(
                        cb + j * 8192 + kq * 4096 + w * 1024 + ln * 16);
#pragma unroll
                for (int mg = 0; mg < 4; ++mg) {
                    const int ko = kc + kq * 64 + mg * 16 * NIN;
                    const v4i A0 = *reinterpret_cast<const v4i*>(xt0 + ko);
                    const v4i A1 = *reinterpret_cast<const v4i*>(xt1 + ko);
#pragma unroll
                    for (int j = 0; j < Q; ++j) {
                        acc0[mg][j] = __builtin_amdgcn_mfma_i32_16x16x64_i8(
                            A0, B[j], acc0[mg][j], 0, 0, 0);
                        acc1[mg][j] = __builtin_amdgcn_mfma_i32_16x16x64_i8(
                            A1, B[j], acc1[mg][j], 0, 0, 0);
                    }
                }
            }
            __syncthreads();   // drains B-DMA (issued one full iter earlier)
        }

        // recombine digits (exact fp64), LIF, emit spikes for t-pair
        const int ocol = o0 + 16 * w + lm;
#pragma unroll
        for (int tt = 0; tt < 2; ++tt) {
            const int t = 2 * tb + tt;
#pragma unroll
            for (int mg = 0; mg < 4; ++mg) {
#pragma unroll
                for (int r = 0; r < 4; ++r) {
                    const int d0 = tt ? acc1[mg][0][r] : acc0[mg][0][r];
                    const int d1 = tt ? acc1[mg][1][r] : acc0[mg][1][r];
                    const int d2 = tt ? acc1[mg][2][r] : acc0[mg][2][r];
                    const int d3 = tt ? acc1[mg][3][r] : acc0[mg][3][r];
                    double sm = (double)d3;
                    sm = sm * 256.0 + (double)d2;
                    sm = sm * 256.0 + (double)d1;
                    sm = sm * 256.0 + (double)d0;
                    const double cur = sm * INV_SCALE;

                    const int e = mg * 4 + r;
                    I[e] = alpha_s * I[e] + cur;
                    V[e] = alpha_m * V[e] + dtm * I[e];
                    const double sp = (V[e] >= 1.0) ? 1.0 : 0.0;
                    V[e] *= (1.0 - sp);

                    const int brow = b0 + 16 * mg + 4 * qd + r;
                    out[(size_t)t * BATCH * NOUT + (size_t)brow * NOUT + ocol]
                        = (float)sp;
                }
            }
        }
    }
}

// ------------------------------------------------ fallback: verified R1 kernel
constexpr int TBF = 64, TOF = 64, KCF = 64, LDPF = KCF + 4;

__global__ __launch_bounds__(256, 2)
void snn_fused(const float* __restrict__ x,
               const float* __restrict__ w,
               float* __restrict__ out)
{
    const int o0  = blockIdx.x * TOF;
    const int b0  = blockIdx.y * TBF;
    const int tid = threadIdx.x;
    const int tx  = tid & 15;
    const int ty  = tid >> 4;

    __shared__ float xs[TBF][LDPF];
    __shared__ float ws[TOF][LDPF];

    const int lr = tid >> 2;
    const int lc = (tid & 3) << 4;

    double V[4][4], I[4][4];
#pragma unroll
    for (int i = 0; i < 4; ++i)
#pragma unroll
        for (int j = 0; j < 4; ++j) { V[i][j] = 0.0; I[i][j] = 0.0; }

    const double alpha_m = 1.0 - 1.0 / 20.0;
    const double alpha_s = 1.0 - 1.0 / 5.0;
    const double dtm     = 1.0 / 20.0;

    for (int t = 0; t < T_STEPS; ++t) {
        const float* xt = x + (size_t)t * BATCH * NIN;
        double c[4][4];
#pragma unroll
        for (int i = 0; i < 4; ++i)
#pragma unroll
            for (int j = 0; j < 4; ++j) c[i][j] = 0.0;

        for (int kc = 0; kc < NIN; kc += KCF) {
            __syncthreads();
            {
                const float4* xg = reinterpret_cast<const float4*>(
                    xt + (size_t)(b0 + lr) * NIN + kc + lc);
                const float4* wg = reinterpret_cast<const float4*>(
                    w + (size_t)(o0 + lr) * NIN + kc + lc);
#pragma unroll
                for (int q = 0; q < 4; ++q) {
                    float4 xv = xg[q];
                    float4 wv4 = wg[q];
                    const int cbi = lc + q * 4;
                    xs[lr][cbi + 0] = xv.x;  xs[lr][cbi + 1] = xv.y;
                    xs[lr][cbi + 2] = xv.z;  xs[lr][cbi + 3] = xv.w;
                    ws[lr][cbi + 0] = wv4.x; ws[lr][cbi + 1] = wv4.y;
                    ws[lr][cbi + 2] = wv4.z; ws[lr][cbi + 3] = wv4.w;
                }
            }
            __syncthreads();

#pragma unroll 8
            for (int k = 0; k < KCF; ++k) {
                float xa[4], wa[4];
#pragma unroll
                for (int i = 0; i < 4; ++i) xa[i] = xs[ty * 4 + i][k];
#pragma unroll
                for (int j = 0; j < 4; ++j) wa[j] = ws[tx * 4 + j][k];
#pragma unroll
                for (int i = 0; i < 4; ++i)
#pragma unroll
                    for (int j = 0; j < 4; ++j)
                        c[i][j] += (double)xa[i] * (double)wa[j];
            }
        }

#pragma unroll
        for (int i = 0; i < 4; ++i) {
            float sv[4];
#pragma unroll
            for (int j = 0; j < 4; ++j) {
                I[i][j] = alpha_s * I[i][j] + c[i][j];
                V[i][j] = alpha_m * V[i][j] + dtm * I[i][j];
                const double sp = (V[i][j] >= 1.0) ? 1.0 : 0.0;
                V[i][j] *= (1.0 - sp);
                sv[j] = (float)sp;
            }
            const size_t oidx = (size_t)t * BATCH * NOUT
                              + (size_t)(b0 + ty * 4 + i) * NOUT
                              + (size_t)(o0 + tx * 4);
            *reinterpret_cast<float4*>(out + oidx) =
                make_float4(sv[0], sv[1], sv[2], sv[3]);
        }
    }
}

extern "C" void kernel_launch(void* const* d_in, const int* in_sizes, int n_in,
                              void* d_out, int out_size, void* d_ws, size_t ws_size,
                              hipStream_t stream) {
    const float* x = (const float*)d_in[0];
    const float* w = (const float*)d_in[1];
    float* out     = (float*)d_out;
    (void)in_sizes; (void)n_in; (void)out_size;

    if (ws_size >= WS_NEEDED) {
        int8_t* xi    = (int8_t*)d_ws;
        int8_t* limbs = xi + XI8_BYTES;
        prep_x<<<(int)(XI8_BYTES / 16 / 256), 256, 0, stream>>>(x, xi);
        prep_limbs<<<(int)(PLANE_BYTES / 4 / 256), 256, 0, stream>>>(w, limbs);
        snn_i8<<<512, 256, 0, stream>>>(xi, limbs, out);
    } else {
        dim3 grid(NOUT / TOF, BATCH / TBF);
        snn_fused<<<grid, dim3(256), 0, stream>>>(x, w, out);
    }
}

// Round 6
// 1032.650 us; speedup vs baseline: 1.0934x; 1.0934x over previous
//
#include <hip/hip_runtime.h>
#include <stdint.h>

// SpikingLinearLayer: spikes = LIF_scan(x @ W^T)  -- exact i8-limb MFMA path.
//   x: [20, 1024, 2048] fp32 binary; W: [2048, 2048] fp32; out fp32 binary.
//
// R5 -> R6:
//  * REVERT R5's A-direct-global loads: global A loads share the vmcnt queue
//    with the B-prefetch DMAs (in-order retire), so waiting on A drained the
//    next iter's prefetch -> pipeline serialized (MfmaUtil 15%). Back to the
//    R4 all-LDS staging (proven 491 us, 0 conflicts).
//  * R4 was GRID-CAPPED at 2 blocks/CU (512 blocks, occupancy 23%): only 2
//    barrier domains -> ~55% idle at per-iter __syncthreads drains. R6 uses
//    thin 32b x 64o blocks, grid 1024, __launch_bounds__(256,3) -> 3
//    blocks/CU = 3 independent barrier domains; per-block staging halves
//    (5 DMAs/wave: 1 A + 4 B), LDS 2x20KB = 40KB/block.
//  * Q=4 limbs (scale 2^30) exact-integer GEMM + fp64 recombine/LIF
//    (verified absmax 0.0 in R3/R4/R5). Digit sums <= 2^18, recombine exact.

constexpr int T_STEPS = 20;
constexpr int BATCH   = 1024;
constexpr int NIN     = 2048;
constexpr int NOUT    = 2048;

constexpr int    Q         = 4;
constexpr double SCALE     = 1073741824.0;     // 2^30
constexpr double INV_SCALE = 1.0 / SCALE;

constexpr size_t XI8_BYTES   = (size_t)T_STEPS * BATCH * NIN;        // 40 MB
constexpr size_t PLANE_BYTES = (size_t)NOUT * NIN;                   // 4 MB
constexpr size_t WS_NEEDED   = XI8_BYTES + (size_t)Q * PLANE_BYTES;  // 56 MB

typedef int v4i __attribute__((ext_vector_type(4)));

// async 16B/lane global->LDS DMA: lds dst = uniform base + lane*16
__device__ __forceinline__ void dma16(const int8_t* g, const int8_t* l) {
    __builtin_amdgcn_global_load_lds(
        (const __attribute__((address_space(1))) void*)(uintptr_t)g,
        (__attribute__((address_space(3))) void*)(uint32_t)(uintptr_t)l,
        16, 0, 0);
}

// ---------------------------------------------------------------- prep: x -> i8
__global__ void prep_x(const float* __restrict__ x, int8_t* __restrict__ xi) {
    const int idx = blockIdx.x * blockDim.x + threadIdx.x;   // 16 elems each
    const float4* xg = reinterpret_cast<const float4*>(x) + idx * 4;
    int8_t c[16];
#pragma unroll
    for (int q = 0; q < 4; ++q) {
        const float4 v = xg[q];
        c[q * 4 + 0] = (int8_t)(v.x != 0.0f);
        c[q * 4 + 1] = (int8_t)(v.y != 0.0f);
        c[q * 4 + 2] = (int8_t)(v.z != 0.0f);
        c[q * 4 + 3] = (int8_t)(v.w != 0.0f);
    }
    reinterpret_cast<v4i*>(xi)[idx] = *reinterpret_cast<const v4i*>(c);
}

// ------------------------------------------------- prep: W -> 4 base-256 digits
__global__ void prep_limbs(const float* __restrict__ w, int8_t* __restrict__ limbs) {
    const int idx = blockIdx.x * blockDim.x + threadIdx.x;   // 4 weights each
    const float4 wv = reinterpret_cast<const float4*>(w)[idx];
    const float wf[4] = {wv.x, wv.y, wv.z, wv.w};
    int8_t d[Q][4];
#pragma unroll
    for (int e = 0; e < 4; ++e) {
        long long M = llrint((double)wf[e] * SCALE);         // |M| < 2^30
#pragma unroll
        for (int j = 0; j < Q - 1; ++j) {
            const int dj = (int)((M + 128) & 255) - 128;
            d[j][e] = (int8_t)dj;
            M = (M - dj) >> 8;                               // exact
        }
        d[Q - 1][e] = (int8_t)M;                             // |top| <= 65
    }
#pragma unroll
    for (int j = 0; j < Q; ++j)
        reinterpret_cast<char4*>(limbs + (size_t)j * PLANE_BYTES)[idx] =
            make_char4(d[j][0], d[j][1], d[j][2], d[j][3]);
}

// --------------------------------------------------------------- hot: i8 GEMMs
constexpr int TB     = 32;                  // batch tile (thin)
constexpr int TO     = 64;                  // out tile
constexpr int KC     = 64;
constexpr int NKC    = NIN / KC;            // 32
constexpr int NTB    = T_STEPS / 2;         // 10 t-pairs
constexpr int NITER  = NTB * NKC;           // 320
constexpr int BUF_B  = 20480;               // A 4KB (2t x 32b x 64k) + B 16KB
constexpr int B_OFF  = 4096;

__global__ __launch_bounds__(256, 3)
void snn_i8(const int8_t* __restrict__ xi, const int8_t* __restrict__ limbs,
            float* __restrict__ out)
{
    // XCD swizzle: 4 o-tiles pinned per XCD -> limb set 2 MB in 4 MB L2
    const int bid   = blockIdx.x;            // 0..1023
    const int xcd   = bid & 7;
    const int sub   = bid >> 3;              // 0..127
    const int otile = xcd * 4 + (sub & 3);   // 0..31
    const int btile = sub >> 2;              // 0..31
    const int o0 = otile * TO, b0 = btile * TB;

    const int tid  = threadIdx.x;
    const int w    = tid >> 6;     // wave id = o j-group (16 cols each)
    const int ln   = tid & 63;
    const int lm   = ln & 15;
    const int qd   = ln >> 4;

    __shared__ __align__(16) int8_t lds[2][BUF_B];

    // staging roles: wave w stages A(tloc = w>>1, mg = w&1) + B(all 4 limbs,
    // its own 16-o-row group). Source lane ln -> row lm, bytes qd*16 (matches
    // the slot order base + ln*16 the DMA deposits and the MFMA frag reads).
    const int a_row  = (b0 + 16 * (w & 1) + lm) * NIN + qd * 16;  // + t*B*NIN + kc
    const int l_lane = (o0 + 16 * w + lm) * NIN + qd * 16;        // + j*PLANE + kc
    const int tloc   = w >> 1;

    // LIF state: lane elems e = mg*4+r -> b = b0+16mg+4qd+r, o = o0+16w+lm
    double V[8], I[8];
#pragma unroll
    for (int e = 0; e < 8; ++e) { V[e] = 0.0; I[e] = 0.0; }

    const double alpha_m = 1.0 - 1.0 / 20.0;
    const double alpha_s = 1.0 - 1.0 / 5.0;
    const double dtm     = 1.0 / 20.0;

    // A slot: tloc*2048 + mg*1024 + ln*16 ; B slot: B_OFF + j*4096 + w*1024 + ln*16
    auto stage = [&](int s) {
        const int tb = s >> 5;
        const int kc = (s & 31) << 6;
        int8_t* lb = &lds[s & 1][0];
        dma16(xi + (size_t)(2 * tb + tloc) * BATCH * NIN + kc + a_row,
              lb + tloc * 2048 + (w & 1) * 1024);
#pragma unroll
        for (int j = 0; j < Q; ++j)
            dma16(limbs + (size_t)j * PLANE_BYTES + kc + l_lane,
                  lb + B_OFF + j * 4096 + w * 1024);
    };

    stage(0);
    __syncthreads();

    int s = 0;
    for (int tb = 0; tb < NTB; ++tb) {
        v4i acc0[2][4], acc1[2][4];   // [mg][limb]
#pragma unroll
        for (int mg = 0; mg < 2; ++mg)
#pragma unroll
            for (int j = 0; j < Q; ++j) {
                acc0[mg][j] = (v4i){0, 0, 0, 0};
                acc1[mg][j] = (v4i){0, 0, 0, 0};
            }

        for (int kci = 0; kci < NKC; ++kci, ++s) {
            if (s + 1 < NITER) stage(s + 1);            // async prefetch

            const int8_t* cb = &lds[s & 1][0];
            v4i Bf[4];
#pragma unroll
            for (int j = 0; j < Q; ++j)
                Bf[j] = *reinterpret_cast<const v4i*>(
                    cb + B_OFF + j * 4096 + w * 1024 + ln * 16);
            v4i Af[2][2];
#pragma unroll
            for (int tl = 0; tl < 2; ++tl)
#pragma unroll
                for (int mg = 0; mg < 2; ++mg)
                    Af[tl][mg] = *reinterpret_cast<const v4i*>(
                        cb + tl * 2048 + mg * 1024 + ln * 16);

#pragma unroll
            for (int mg = 0; mg < 2; ++mg)
#pragma unroll
                for (int j = 0; j < Q; ++j) {
                    acc0[mg][j] = __builtin_amdgcn_mfma_i32_16x16x64_i8(
                        Af[0][mg], Bf[j], acc0[mg][j], 0, 0, 0);
                    acc1[mg][j] = __builtin_amdgcn_mfma_i32_16x16x64_i8(
                        Af[1][mg], Bf[j], acc1[mg][j], 0, 0, 0);
                }
            __syncthreads();   // drains DMA (issued one full iter earlier)
        }

        // recombine digits (exact fp64), LIF, emit spikes for t-pair
        const int ocol = o0 + 16 * w + lm;
#pragma unroll
        for (int tt = 0; tt < 2; ++tt) {
            const int t = 2 * tb + tt;
#pragma unroll
            for (int mg = 0; mg < 2; ++mg) {
#pragma unroll
                for (int r = 0; r < 4; ++r) {
                    const int d0 = tt ? acc1[mg][0][r] : acc0[mg][0][r];
                    const int d1 = tt ? acc1[mg][1][r] : acc0[mg][1][r];
                    const int d2 = tt ? acc1[mg][2][r] : acc0[mg][2][r];
                    const int d3 = tt ? acc1[mg][3][r] : acc0[mg][3][r];
                    double sm = (double)d3;
                    sm = sm * 256.0 + (double)d2;
                    sm = sm * 256.0 + (double)d1;
                    sm = sm * 256.0 + (double)d0;
                    const double cur = sm * INV_SCALE;

                    const int e = mg * 4 + r;
                    I[e] = alpha_s * I[e] + cur;
                    V[e] = alpha_m * V[e] + dtm * I[e];
                    const double sp = (V[e] >= 1.0) ? 1.0 : 0.0;
                    V[e] *= (1.0 - sp);

                    const int brow = b0 + 16 * mg + 4 * qd + r;
                    out[(size_t)t * BATCH * NOUT + (size_t)brow * NOUT + ocol]
                        = (float)sp;
                }
            }
        }
    }
}

// ------------------------------------------------ fallback: verified R1 kernel
constexpr int TBF = 64, TOF = 64, KCF = 64, LDPF = KCF + 4;

__global__ __launch_bounds__(256, 2)
void snn_fused(const float* __restrict__ x,
               const float* __restrict__ w,
               float* __restrict__ out)
{
    const int o0  = blockIdx.x * TOF;
    const int b0  = blockIdx.y * TBF;
    const int tid = threadIdx.x;
    const int tx  = tid & 15;
    const int ty  = tid >> 4;

    __shared__ float xs[TBF][LDPF];
    __shared__ float ws[TOF][LDPF];

    const int lr = tid >> 2;
    const int lc = (tid & 3) << 4;

    double V[4][4], I[4][4];
#pragma unroll
    for (int i = 0; i < 4; ++i)
#pragma unroll
        for (int j = 0; j < 4; ++j) { V[i][j] = 0.0; I[i][j] = 0.0; }

    const double alpha_m = 1.0 - 1.0 / 20.0;
    const double alpha_s = 1.0 - 1.0 / 5.0;
    const double dtm     = 1.0 / 20.0;

    for (int t = 0; t < T_STEPS; ++t) {
        const float* xt = x + (size_t)t * BATCH * NIN;
        double c[4][4];
#pragma unroll
        for (int i = 0; i < 4; ++i)
#pragma unroll
            for (int j = 0; j < 4; ++j) c[i][j] = 0.0;

        for (int kc = 0; kc < NIN; kc += KCF) {
            __syncthreads();
            {
                const float4* xg = reinterpret_cast<const float4*>(
                    xt + (size_t)(b0 + lr) * NIN + kc + lc);
                const float4* wg = reinterpret_cast<const float4*>(
                    w + (size_t)(o0 + lr) * NIN + kc + lc);
#pragma unroll
                for (int q = 0; q < 4; ++q) {
                    float4 xv = xg[q];
                    float4 wv4 = wg[q];
                    const int cbi = lc + q * 4;
                    xs[lr][cbi + 0] = xv.x;  xs[lr][cbi + 1] = xv.y;
                    xs[lr][cbi + 2] = xv.z;  xs[lr][cbi + 3] = xv.w;
                    ws[lr][cbi + 0] = wv4.x; ws[lr][cbi + 1] = wv4.y;
                    ws[lr][cbi + 2] = wv4.z; ws[lr][cbi + 3] = wv4.w;
                }
            }
            __syncthreads();

#pragma unroll 8
            for (int k = 0; k < KCF; ++k) {
                float xa[4], wa[4];
#pragma unroll
                for (int i = 0; i < 4; ++i) xa[i] = xs[ty * 4 + i][k];
#pragma unroll
                for (int j = 0; j < 4; ++j) wa[j] = ws[tx * 4 + j][k];
#pragma unroll
                for (int i = 0; i < 4; ++i)
#pragma unroll
                    for (int j = 0; j < 4; ++j)
                        c[i][j] += (double)xa[i] * (double)wa[j];
            }
        }

#pragma unroll
        for (int i = 0; i < 4; ++i) {
            float sv[4];
#pragma unroll
            for (int j = 0; j < 4; ++j) {
                I[i][j] = alpha_s * I[i][j] + c[i][j];
                V[i][j] = alpha_m * V[i][j] + dtm * I[i][j];
                const double sp = (V[i][j] >= 1.0) ? 1.0 : 0.0;
                V[i][j] *= (1.0 - sp);
                sv[j] = (float)sp;
            }
            const size_t oidx = (size_t)t * BATCH * NOUT
                              + (size_t)(b0 + ty * 4 + i) * NOUT
                              + (size_t)(o0 + tx * 4);
            *reinterpret_cast<float4*>(out + oidx) =
                make_float4(sv[0], sv[1], sv[2], sv[3]);
        }
    }
}

extern "C" void kernel_launch(void* const* d_in, const int* in_sizes, int n_in,
                              void* d_out, int out_size, void* d_ws, size_t ws_size,
                              hipStream_t stream) {
    const float* x = (const float*)d_in[0];
    const float* w = (const float*)d_in[1];
    float* out     = (float*)d_out;
    (void)in_sizes; (void)n_in; (void)out_size;

    if (ws_size >= WS_NEEDED) {
        int8_t* xi    = (int8_t*)d_ws;
        int8_t* limbs = xi + XI8_BYTES;
        prep_x<<<(int)(XI8_BYTES / 16 / 256), 256, 0, stream>>>(x, xi);
        prep_limbs<<<(int)(PLANE_BYTES / 4 / 256), 256, 0, stream>>>(w, limbs);
        snn_i8<<<1024, 256, 0, stream>>>(xi, limbs, out);
    } else {
        dim3 grid(NOUT / TOF, BATCH / TBF);
        snn_fused<<<grid, dim3(256), 0, stream>>>(x, w, out);
    }
}

// Round 7
// 720.405 us; speedup vs baseline: 1.5673x; 1.4334x over previous
//
#include <hip/hip_runtime.h>
#include <stdint.h>

// SpikingLinearLayer: spikes = LIF_scan(x @ W^T)  -- exact i8-limb MFMA path.
//   x: [20, 1024, 2048] fp32 binary; W: [2048, 2048] fp32; out fp32 binary.
//
// R6 -> R7: back to R4's 64b x 64o tile (best: 491 us), but replace the
// __syncthreads-per-iter K-loop (whose compiler-emitted s_waitcnt vmcnt(0)
// drains the just-issued prefetch DMAs every iteration -- the documented
// m97 barrier plateau) with the AITER-style pipeline:
//   triple-buffer ring (3 x 24 KB), per iter:
//     s_waitcnt vmcnt(6)   <- waits only the 2-iter-old DMA group (6 ops),
//                             fresh prefetch stays in flight
//     s_barrier (raw)      <- cross-wave visibility of that group's deposits
//     issue stage(s+2)     <- after barrier: nobody still reads that slot
//     ds_read frags, 32 MFMA/wave
// Race proof: (1) wave's own group-s retired before its barrier (vmcnt<=6,
// groups s,s+1 outstanding max 12 -> <=6 forces s drained); barrier makes
// that true for ALL waves before ANY wave reads buf s. (2) stage(s+2)
// overwrites slot (s-1)%3, whose readers (iter s-1) finished their ds_reads
// before arriving at iter-s barrier; issue is after that barrier.
// Tail: last iter waits vmcnt(0).
//
// Q=4 limbs (scale 2^30) exact-integer GEMM + fp64 recombine/LIF (verified
// absmax 0.0 R3-R6). Digit sums <= 2^18; recombine exact in fp64.

constexpr int T_STEPS = 20;
constexpr int BATCH   = 1024;
constexpr int NIN     = 2048;
constexpr int NOUT    = 2048;

constexpr int    Q         = 4;
constexpr double SCALE     = 1073741824.0;     // 2^30
constexpr double INV_SCALE = 1.0 / SCALE;

constexpr size_t XI8_BYTES   = (size_t)T_STEPS * BATCH * NIN;        // 40 MB
constexpr size_t PLANE_BYTES = (size_t)NOUT * NIN;                   // 4 MB
constexpr size_t WS_NEEDED   = XI8_BYTES + (size_t)Q * PLANE_BYTES;  // 56 MB

typedef int v4i __attribute__((ext_vector_type(4)));

// async 16B/lane global->LDS DMA: lds dst = uniform base + lane*16
__device__ __forceinline__ void dma16(const int8_t* g, const int8_t* l) {
    __builtin_amdgcn_global_load_lds(
        (const __attribute__((address_space(1))) void*)(uintptr_t)g,
        (__attribute__((address_space(3))) void*)(uint32_t)(uintptr_t)l,
        16, 0, 0);
}

#define FENCE()  asm volatile("" ::: "memory")
#define WAITV(N) asm volatile("s_waitcnt vmcnt(" #N ")" ::: "memory")

// ---------------------------------------------------------------- prep: x -> i8
__global__ void prep_x(const float* __restrict__ x, int8_t* __restrict__ xi) {
    const int idx = blockIdx.x * blockDim.x + threadIdx.x;   // 16 elems each
    const float4* xg = reinterpret_cast<const float4*>(x) + idx * 4;
    int8_t c[16];
#pragma unroll
    for (int q = 0; q < 4; ++q) {
        const float4 v = xg[q];
        c[q * 4 + 0] = (int8_t)(v.x != 0.0f);
        c[q * 4 + 1] = (int8_t)(v.y != 0.0f);
        c[q * 4 + 2] = (int8_t)(v.z != 0.0f);
        c[q * 4 + 3] = (int8_t)(v.w != 0.0f);
    }
    reinterpret_cast<v4i*>(xi)[idx] = *reinterpret_cast<const v4i*>(c);
}

// ------------------------------------------------- prep: W -> 4 base-256 digits
__global__ void prep_limbs(const float* __restrict__ w, int8_t* __restrict__ limbs) {
    const int idx = blockIdx.x * blockDim.x + threadIdx.x;   // 4 weights each
    const float4 wv = reinterpret_cast<const float4*>(w)[idx];
    const float wf[4] = {wv.x, wv.y, wv.z, wv.w};
    int8_t d[Q][4];
#pragma unroll
    for (int e = 0; e < 4; ++e) {
        long long M = llrint((double)wf[e] * SCALE);         // |M| < 2^30
#pragma unroll
        for (int j = 0; j < Q - 1; ++j) {
            const int dj = (int)((M + 128) & 255) - 128;
            d[j][e] = (int8_t)dj;
            M = (M - dj) >> 8;                               // exact
        }
        d[Q - 1][e] = (int8_t)M;                             // |top| <= 65
    }
#pragma unroll
    for (int j = 0; j < Q; ++j)
        reinterpret_cast<char4*>(limbs + (size_t)j * PLANE_BYTES)[idx] =
            make_char4(d[j][0], d[j][1], d[j][2], d[j][3]);
}

// --------------------------------------------------------------- hot: i8 GEMMs
constexpr int KC     = 64;
constexpr int NKC    = NIN / KC;            // 32
constexpr int NTB    = T_STEPS / 2;         // 10 t-pairs
constexpr int NITER  = NTB * NKC;           // 320
constexpr int BUF_B  = 24576;               // A(2t)*4KB + B(4 planes)*4KB
constexpr int A_OFF  = 0;
constexpr int B_OFF  = 8192;

__global__ __launch_bounds__(256, 2)
void snn_i8(const int8_t* __restrict__ xi, const int8_t* __restrict__ limbs,
            float* __restrict__ out)
{
    // XCD swizzle: 4 o-tiles pinned per XCD -> limb set 2 MB in 4 MB L2
    const int bid   = blockIdx.x;
    const int xcd   = bid & 7;
    const int sub   = bid >> 3;
    const int otile = xcd * 4 + (sub & 3);
    const int btile = sub >> 2;
    const int o0 = otile * 64, b0 = btile * 64;

    const int tid  = threadIdx.x;
    const int w    = tid >> 6;     // wave id = o j-group; stages A slot mg=w
    const int ln   = tid & 63;
    const int lm   = ln & 15;
    const int qd   = ln >> 4;

    __shared__ __align__(16) int8_t lds[3][BUF_B];   // 72 KB ring

    // per-lane global byte offsets (lane ln deposits at base + ln*16)
    const size_t x_lane = (size_t)(b0 + 16 * w + lm) * NIN + qd * 16;
    const size_t l_lane = (size_t)(o0 + 16 * w + lm) * NIN + qd * 16;

    // LIF state: lane elems e = mg*4+r -> b = b0+16mg+4qd+r, o = o0+16w+lm
    double V[16], I[16];
#pragma unroll
    for (int e = 0; e < 16; ++e) { V[e] = 0.0; I[e] = 0.0; }

    const double alpha_m = 1.0 - 1.0 / 20.0;
    const double alpha_s = 1.0 - 1.0 / 5.0;
    const double dtm     = 1.0 / 20.0;

    // stage iter s into lds[s%3]; 6 DMAs per wave (A t0, A t1, B j=0..3)
    auto stage = [&](int s) {
        const int tb = s >> 5;
        const int kc = (s & 31) << 6;
        const int8_t* xb = xi + (size_t)(2 * tb) * BATCH * NIN + kc + x_lane;
        int8_t* lb = &lds[s % 3][0];
        dma16(xb,                       lb + A_OFF + 0    + w * 1024);
        dma16(xb + (size_t)BATCH * NIN, lb + A_OFF + 4096 + w * 1024);
#pragma unroll
        for (int j = 0; j < Q; ++j)
            dma16(limbs + (size_t)j * PLANE_BYTES + kc + l_lane,
                  lb + B_OFF + j * 4096 + w * 1024);
    };

    stage(0);
    stage(1);

    int s = 0;
    for (int tb = 0; tb < NTB; ++tb) {
        v4i acc0[4][4], acc1[4][4];   // [mg][limb]
#pragma unroll
        for (int mg = 0; mg < 4; ++mg)
#pragma unroll
            for (int j = 0; j < Q; ++j) {
                acc0[mg][j] = (v4i){0, 0, 0, 0};
                acc1[mg][j] = (v4i){0, 0, 0, 0};
            }

        for (int kci = 0; kci < NKC; ++kci, ++s) {
            // wait own 2-iter-old DMA group (never the fresh prefetch)
            if (s == NITER - 1) { WAITV(0); } else { WAITV(6); }
            FENCE();
            __builtin_amdgcn_s_barrier();   // raw barrier: no vmcnt(0) drain
            FENCE();
            if (s + 2 < NITER) stage(s + 2);   // overwrite slot (s-1)%3: safe,
                                               // its readers passed this barrier
            const int8_t* cb = &lds[s % 3][0];
            v4i Bf[4];
#pragma unroll
            for (int j = 0; j < Q; ++j)
                Bf[j] = *reinterpret_cast<const v4i*>(
                    cb + B_OFF + j * 4096 + w * 1024 + ln * 16);
#pragma unroll
            for (int mg = 0; mg < 4; ++mg) {
                const v4i A0 = *reinterpret_cast<const v4i*>(
                    cb + A_OFF + 0    + mg * 1024 + ln * 16);
                const v4i A1 = *reinterpret_cast<const v4i*>(
                    cb + A_OFF + 4096 + mg * 1024 + ln * 16);
#pragma unroll
                for (int j = 0; j < Q; ++j) {
                    acc0[mg][j] = __builtin_amdgcn_mfma_i32_16x16x64_i8(
                        A0, Bf[j], acc0[mg][j], 0, 0, 0);
                    acc1[mg][j] = __builtin_amdgcn_mfma_i32_16x16x64_i8(
                        A1, Bf[j], acc1[mg][j], 0, 0, 0);
                }
            }
        }

        // recombine digits (exact fp64), LIF, emit spikes for t-pair
        const int ocol = o0 + 16 * w + lm;
#pragma unroll
        for (int tt = 0; tt < 2; ++tt) {
            const int t = 2 * tb + tt;
#pragma unroll
            for (int mg = 0; mg < 4; ++mg) {
#pragma unroll
                for (int r = 0; r < 4; ++r) {
                    const int d0 = tt ? acc1[mg][0][r] : acc0[mg][0][r];
                    const int d1 = tt ? acc1[mg][1][r] : acc0[mg][1][r];
                    const int d2 = tt ? acc1[mg][2][r] : acc0[mg][2][r];
                    const int d3 = tt ? acc1[mg][3][r] : acc0[mg][3][r];
                    double sm = (double)d3;
                    sm = sm * 256.0 + (double)d2;
                    sm = sm * 256.0 + (double)d1;
                    sm = sm * 256.0 + (double)d0;
                    const double cur = sm * INV_SCALE;

                    const int e = mg * 4 + r;
                    I[e] = alpha_s * I[e] + cur;
                    V[e] = alpha_m * V[e] + dtm * I[e];
                    const double sp = (V[e] >= 1.0) ? 1.0 : 0.0;
                    V[e] *= (1.0 - sp);

                    const int brow = b0 + 16 * mg + 4 * qd + r;
                    out[(size_t)t * BATCH * NOUT + (size_t)brow * NOUT + ocol]
                        = (float)sp;
                }
            }
        }
    }
}

// ------------------------------------------------ fallback: verified R1 kernel
constexpr int TBF = 64, TOF = 64, KCF = 64, LDPF = KCF + 4;

__global__ __launch_bounds__(256, 2)
void snn_fused(const float* __restrict__ x,
               const float* __restrict__ w,
               float* __restrict__ out)
{
    const int o0  = blockIdx.x * TOF;
    const int b0  = blockIdx.y * TBF;
    const int tid = threadIdx.x;
    const int tx  = tid & 15;
    const int ty  = tid >> 4;

    __shared__ float xs[TBF][LDPF];
    __shared__ float ws[TOF][LDPF];

    const int lr = tid >> 2;
    const int lc = (tid & 3) << 4;

    double V[4][4], I[4][4];
#pragma unroll
    for (int i = 0; i < 4; ++i)
#pragma unroll
        for (int j = 0; j < 4; ++j) { V[i][j] = 0.0; I[i][j] = 0.0; }

    const double alpha_m = 1.0 - 1.0 / 20.0;
    const double alpha_s = 1.0 - 1.0 / 5.0;
    const double dtm     = 1.0 / 20.0;

    for (int t = 0; t < T_STEPS; ++t) {
        const float* xt = x + (size_t)t * BATCH * NIN;
        double c[4][4];
#pragma unroll
        for (int i = 0; i < 4; ++i)
#pragma unroll
            for (int j = 0; j < 4; ++j) c[i][j] = 0.0;

        for (int kc = 0; kc < NIN; kc += KCF) {
            __syncthreads();
            {
                const float4* xg = reinterpret_cast<const float4*>(
                    xt + (size_t)(b0 + lr) * NIN + kc + lc);
                const float4* wg = reinterpret_cast<const float4*>(
                    w + (size_t)(o0 + lr) * NIN + kc + lc);
#pragma unroll
                for (int q = 0; q < 4; ++q) {
                    float4 xv = xg[q];
                    float4 wv4 = wg[q];
                    const int cbi = lc + q * 4;
                    xs[lr][cbi + 0] = xv.x;  xs[lr][cbi + 1] = xv.y;
                    xs[lr][cbi + 2] = xv.z;  xs[lr][cbi + 3] = xv.w;
                    ws[lr][cbi + 0] = wv4.x; ws[lr][cbi + 1] = wv4.y;
                    ws[lr][cbi + 2] = wv4.z; ws[lr][cbi + 3] = wv4.w;
                }
            }
            __syncthreads();

#pragma unroll 8
            for (int k = 0; k < KCF; ++k) {
                float xa[4], wa[4];
#pragma unroll
                for (int i = 0; i < 4; ++i) xa[i] = xs[ty * 4 + i][k];
#pragma unroll
                for (int j = 0; j < 4; ++j) wa[j] = ws[tx * 4 + j][k];
#pragma unroll
                for (int i = 0; i < 4; ++i)
#pragma unroll
                    for (int j = 0; j < 4; ++j)
                        c[i][j] += (double)xa[i] * (double)wa[j];
            }
        }

#pragma unroll
        for (int i = 0; i < 4; ++i) {
            float sv[4];
#pragma unroll
            for (int j = 0; j < 4; ++j) {
                I[i][j] = alpha_s * I[i][j] + c[i][j];
                V[i][j] = alpha_m * V[i][j] + dtm * I[i][j];
                const double sp = (V[i][j] >= 1.0) ? 1.0 : 0.0;
                V[i][j] *= (1.0 - sp);
                sv[j] = (float)sp;
            }
            const size_t oidx = (size_t)t * BATCH * NOUT
                              + (size_t)(b0 + ty * 4 + i) * NOUT
                              + (size_t)(o0 + tx * 4);
            *reinterpret_cast<float4*>(out + oidx) =
                make_float4(sv[0], sv[1], sv[2], sv[3]);
        }
    }
}

extern "C" void kernel_launch(void* const* d_in, const int* in_sizes, int n_in,
                              void* d_out, int out_size, void* d_ws, size_t ws_size,
                              hipStream_t stream) {
    const float* x = (const float*)d_in[0];
    const float* w = (const float*)d_in[1];
    float* out     = (float*)d_out;
    (void)in_sizes; (void)n_in; (void)out_size;

    if (ws_size >= WS_NEEDED) {
        int8_t* xi    = (int8_t*)d_ws;
        int8_t* limbs = xi + XI8_BYTES;
        prep_x<<<(int)(XI8_BYTES / 16 / 256), 256, 0, stream>>>(x, xi);
        prep_limbs<<<(int)(PLANE_BYTES / 4 / 256), 256, 0, stream>>>(w, limbs);
        snn_i8<<<512, 256, 0, stream>>>(xi, limbs, out);
    } else {
        dim3 grid(NOUT / TOF, BATCH / TBF);
        snn_fused<<<grid, dim3(256), 0, stream>>>(x, w, out);
    }
}